// Round 6
// baseline (1749.567 us; speedup 1.0000x reference)
//
#include <hip/hip_runtime.h>
#include <math.h>

namespace {
constexpr int H = 128, W = 128, NB = 2;
constexpr int HW = H * W;
constexpr int WP = 130, HP = 130, HWP = WP * HP;   // padded image
constexpr int NTHR = 256;
constexpr int DG = 16, CPG = 8, DCN_CIN = 128, DCN_COUT = 64;

// workspace layout (floats). Total = 18,350,080 f = 73,400,320 B (proven size).
// hA [0, 2163200) ; hB [2163200, 4326400) ; pin [4326400, 10951200)
// o4 [4194304, 18350080)  -- overlaps pin (dead by conv4) and hB tail (dead by conv4)
constexpr size_t OFF_HA  = 0;
constexpr size_t OFF_HB  = 2163200;
constexpr size_t OFF_PIN = 4326400;
constexpr size_t OFF_O4  = 4194304;
}

// ---------------------------------------------------------------------------
// Prep: pack ef(192)+flow1(2)+flow2(2) -> padded pin interior, and zero the
// 1-px borders of pin, hA, hB (ws is poisoned each call).
// ---------------------------------------------------------------------------
__global__ __launch_bounds__(NTHR) void prep_k(
    const float* __restrict__ ef, const float* __restrict__ f1,
    const float* __restrict__ f2,
    float* __restrict__ pin, float* __restrict__ hA, float* __restrict__ hB)
{
  constexpr int PACK_N  = NB * 196 * HW;          // 6,422,528
  constexpr int BORD_CH = NB * (196 + 64 + 64);   // 648 channels with borders
  constexpr int BORD_N  = BORD_CH * 516;
  const int total = PACK_N + BORD_N;
  for (int gid = blockIdx.x * NTHR + threadIdx.x; gid < total;
       gid += gridDim.x * NTHR) {
    if (gid < PACK_N) {
      const int b = gid / (196 * HW);
      const int r = gid - b * 196 * HW;
      const int c = r / HW;
      const int p = r - c * HW;
      const int y = p / W, x = p - y * W;
      float v;
      if (c < 192)      v = ef[(b * 192 + c) * HW + p];
      else if (c < 194) v = f1[(b * 2 + (c - 192)) * HW + p];
      else              v = f2[(b * 2 + (c - 194)) * HW + p];
      pin[(size_t)(b * 196 + c) * HWP + (y + 1) * WP + (x + 1)] = v;
    } else {
      const int k  = gid - PACK_N;
      const int ch = k / 516;
      const int e  = k - ch * 516;
      float* base;
      if (ch < NB * 196)            base = pin + (size_t)ch * HWP;
      else if (ch < NB * 196 + NB * 64) base = hA + (size_t)(ch - NB * 196) * HWP;
      else                          base = hB + (size_t)(ch - NB * 196 - NB * 64) * HWP;
      int off;
      if (e < 260) { const int rr = (e < 130) ? 0 : (HP - 1); off = rr * WP + (e % 130); }
      else { const int e2 = e - 260; const int y = 1 + (e2 & 127); off = y * WP + ((e2 < 128) ? 0 : (WP - 1)); }
      base[off] = 0.f;
    }
  }
}

// ---------------------------------------------------------------------------
// 3x3 conv, padded input (no bounds checks). Software-pipelined staging:
// global->reg prefetch overlaps compute; regs->LDS next round; 1 barrier/round.
// EPI: 1 = leaky(0.1) -> padded out; 2 = offset/mask activation -> unpadded out.
// ---------------------------------------------------------------------------
template<int CIN, int COUT, int CC, int EPI>
__global__ __launch_bounds__(NTHR) void conv3x3_k(
    const float* __restrict__ in,   // padded [NB][CIN][130][130]
    const float* __restrict__ wt,   // [COUT][CIN][9]
    const float* __restrict__ bias,
    const float* __restrict__ fl1, const float* __restrict__ fl2,
    float* __restrict__ out)
{
  constexpr int NST = 4, HN = 18 * 18, IN_E = NST * HN;     // 1296
  constexpr int J_IN = (IN_E + NTHR - 1) / NTHR;            // 6
  constexpr int WT_E = CC * NST * 9;
  constexpr int J_WT = (WT_E + NTHR - 1) / NTHR;
  constexpr int R = CIN / NST;

  __shared__ float s_in[2][NST * HN];
  __shared__ float s_wt[2][CC * NST * 12];

  const int t    = threadIdx.x;
  const int tile = blockIdx.x;
  const int tx0  = (tile & 7) * 16, ty0 = (tile >> 3) * 16;
  const int oc0  = blockIdx.y * CC;
  const int b    = blockIdx.z;
  const int lx   = t & 15, ly = t >> 4;

  const float* inB = in + (size_t)b * CIN * HWP;

  int iadr[J_IN]; bool ivl[J_IN];
  #pragma unroll
  for (int j = 0; j < J_IN; ++j) {
    const int idx = j * NTHR + t;
    ivl[j] = idx < IN_E;
    const int ii = idx / HN, rem = idx - ii * HN;
    const int hy = rem / 18, hx = rem - hy * 18;
    iadr[j] = ivl[j] ? (ii * HWP + (ty0 + hy) * WP + (tx0 + hx)) : 0;
  }
  int wadr[J_WT], wl[J_WT]; bool wvl[J_WT];
  #pragma unroll
  for (int j = 0; j < J_WT; ++j) {
    const int idx = j * NTHR + t;
    wvl[j] = idx < WT_E;
    const int o = idx / 36, r2 = idx - o * 36, ii = r2 / 9, k = r2 - ii * 9;
    wadr[j] = wvl[j] ? (((oc0 + o) * CIN + ii) * 9 + k) : 0;
    wl[j]   = wvl[j] ? ((o * NST + ii) * 12 + k) : 0;
  }

  float rin[J_IN], rwt[J_WT], acc[CC];
  #pragma unroll
  for (int o = 0; o < CC; ++o) acc[o] = 0.f;

  #pragma unroll
  for (int j = 0; j < J_IN; ++j) if (ivl[j]) rin[j] = inB[iadr[j]];
  #pragma unroll
  for (int j = 0; j < J_WT; ++j) if (wvl[j]) rwt[j] = wt[wadr[j]];

  for (int r = 0; r < R; ++r) {
    float* si = s_in[r & 1];
    float* sw = s_wt[r & 1];
    #pragma unroll
    for (int j = 0; j < J_IN; ++j) if (ivl[j]) si[j * NTHR + t] = rin[j];
    #pragma unroll
    for (int j = 0; j < J_WT; ++j) if (wvl[j]) sw[wl[j]] = rwt[j];
    __syncthreads();
    if (r + 1 < R) {            // async prefetch, in flight during compute
      const float* ip = inB + (size_t)(r + 1) * NST * HWP;
      const float* wp = wt + (size_t)(r + 1) * NST * 9;
      #pragma unroll
      for (int j = 0; j < J_IN; ++j) if (ivl[j]) rin[j] = ip[iadr[j]];
      #pragma unroll
      for (int j = 0; j < J_WT; ++j) if (wvl[j]) rwt[j] = wp[wadr[j]];
    }
    #pragma unroll
    for (int i = 0; i < NST; ++i) {
      float va[9];
      #pragma unroll
      for (int dy = 0; dy < 3; ++dy)
        #pragma unroll
        for (int dx = 0; dx < 3; ++dx)
          va[dy * 3 + dx] = si[i * HN + (ly + dy) * 18 + (lx + dx)];
      #pragma unroll
      for (int o = 0; o < CC; ++o) {
        const float* wr = &sw[(o * NST + i) * 12];
        #pragma unroll
        for (int k = 0; k < 9; ++k) acc[o] = fmaf(va[k], wr[k], acc[o]);
      }
    }
  }

  if (EPI == 2) {
    const int pix = (ty0 + ly) * W + (tx0 + lx);
    float fv[2][2];
    fv[0][0] = fl1[(b * 2 + 1) * HW + pix];
    fv[0][1] = fl1[(b * 2 + 0) * HW + pix];
    fv[1][0] = fl2[(b * 2 + 1) * HW + pix];
    fv[1][1] = fl2[(b * 2 + 0) * HW + pix];
    #pragma unroll
    for (int o = 0; o < CC; ++o) {
      const int oc = oc0 + o;
      float rr = acc[o] + bias[oc];
      if (oc < 288) {
        const int yx = oc & 1;
        const int g  = (oc >> 1) / 9;
        rr = 10.f * tanhf(rr) + fv[g >= 8 ? 1 : 0][yx];
      } else {
        rr = 1.f / (1.f + expf(-rr));
      }
      out[((size_t)b * COUT + oc) * HW + pix] = rr;
    }
  } else {
    #pragma unroll
    for (int o = 0; o < CC; ++o) {
      const int oc = oc0 + o;
      float rr = acc[o] + bias[oc];
      rr = (rr >= 0.f) ? rr : 0.1f * rr;
      out[((size_t)b * COUT + oc) * HWP + (ty0 + ly + 1) * WP + (tx0 + lx + 1)] = rr;
    }
  }
}

// ---------------------------------------------------------------------------
// Modulated deformable conv on pre-activated offsets/masks.
// ---------------------------------------------------------------------------
template<int CC>
__global__ __launch_bounds__(NTHR) void deform_k(
    const float* __restrict__ x,      // [B,128,H,W] (unpadded input)
    const float* __restrict__ o4,     // [B,432,H,W] activated offset+mask
    const float* __restrict__ dw,     // [64,128,3,3]
    const float* __restrict__ db,
    float* __restrict__ out)
{
  const int t    = threadIdx.x;
  const int tile = blockIdx.x;
  const int oc0  = blockIdx.y * CC;
  const int b    = blockIdx.z;
  const int lx   = t & 15, ly = t >> 4;
  const int hx   = (tile & 7) * 16 + lx;
  const int hy   = (tile >> 3) * 16 + ly;
  const int pix  = hy * W + hx;

  const float* ob = o4 + (size_t)(b * 432) * HW + pix;
  const float* xb = x + (size_t)(b * DCN_CIN) * HW;

  float acc[CC];
  #pragma unroll
  for (int o = 0; o < CC; ++o) acc[o] = 0.f;

  #pragma unroll 1
  for (int g = 0; g < DG; ++g) {
    float w00[9], w01[9], w10[9], w11[9];
    int   i00[9], i01[9], i10[9], i11[9];
    #pragma unroll
    for (int k = 0; k < 9; ++k) {
      const int cb = g * 9 + k;
      const float oy = ob[(2 * cb + 0) * HW];
      const float ox = ob[(2 * cb + 1) * HW];
      const float mk = ob[(288 + cb) * HW];
      const float py  = (float)(hy + k / 3 - 1) + oy;
      const float pxx = (float)(hx + k % 3 - 1) + ox;
      const float y0f = floorf(py), x0f = floorf(pxx);
      const float wy = py - y0f, wx = pxx - x0f;
      const int y0 = (int)y0f, x0 = (int)x0f;
      const bool vy0 = (y0 >= 0) && (y0 < H);
      const bool vy1 = (y0 + 1 >= 0) && (y0 + 1 < H);
      const bool vx0 = (x0 >= 0) && (x0 < W);
      const bool vx1 = (x0 + 1 >= 0) && (x0 + 1 < W);
      const int cy0 = min(max(y0, 0), H - 1);
      const int cy1 = min(max(y0 + 1, 0), H - 1);
      const int cx0 = min(max(x0, 0), W - 1);
      const int cx1 = min(max(x0 + 1, 0), W - 1);
      i00[k] = cy0 * W + cx0; i01[k] = cy0 * W + cx1;
      i10[k] = cy1 * W + cx0; i11[k] = cy1 * W + cx1;
      w00[k] = (vy0 && vx0) ? (1.f - wy) * (1.f - wx) * mk : 0.f;
      w01[k] = (vy0 && vx1) ? (1.f - wy) * wx * mk : 0.f;
      w10[k] = (vy1 && vx0) ? wy * (1.f - wx) * mk : 0.f;
      w11[k] = (vy1 && vx1) ? wy * wx * mk : 0.f;
    }

    #pragma unroll 2
    for (int c = 0; c < CPG; ++c) {
      const float* xc = xb + (size_t)(g * CPG + c) * HW;
      float val[9];
      #pragma unroll
      for (int k = 0; k < 9; ++k)
        val[k] = w00[k] * xc[i00[k]] + w01[k] * xc[i01[k]]
               + w10[k] * xc[i10[k]] + w11[k] * xc[i11[k]];
      const float* wrow = dw + (size_t)(g * CPG + c) * 9;
      #pragma unroll
      for (int o = 0; o < CC; ++o) {
        const float* wo = wrow + (size_t)(oc0 + o) * (DCN_CIN * 9);
        float a = acc[o];
        #pragma unroll
        for (int k = 0; k < 9; ++k) a = fmaf(val[k], wo[k], a);
        acc[o] = a;
      }
    }
  }

  #pragma unroll
  for (int o = 0; o < CC; ++o)
    out[((size_t)b * DCN_COUT + oc0 + o) * HW + pix] = acc[o] + db[oc0 + o];
}

// ---------------------------------------------------------------------------
extern "C" void kernel_launch(void* const* d_in, const int* in_sizes, int n_in,
                              void* d_out, int out_size, void* d_ws, size_t ws_size,
                              hipStream_t stream) {
  const float* x     = (const float*)d_in[0];
  const float* ef    = (const float*)d_in[1];
  const float* fl1   = (const float*)d_in[2];
  const float* fl2   = (const float*)d_in[3];
  const float* w1    = (const float*)d_in[4];
  const float* b1    = (const float*)d_in[5];
  const float* w2    = (const float*)d_in[6];
  const float* b2    = (const float*)d_in[7];
  const float* w3    = (const float*)d_in[8];
  const float* b3    = (const float*)d_in[9];
  const float* w4    = (const float*)d_in[10];
  const float* b4    = (const float*)d_in[11];
  const float* dcn_w = (const float*)d_in[12];
  const float* dcn_b = (const float*)d_in[13];

  float* ws  = (float*)d_ws;
  float* hA  = ws + OFF_HA;
  float* hB  = ws + OFF_HB;
  float* pin = ws + OFF_PIN;
  float* o4  = ws + OFF_O4;

  const dim3 blk(NTHR);
  prep_k<<<2048, blk, 0, stream>>>(ef, fl1, fl2, pin, hA, hB);
  // conv1: 196 -> 64, leaky
  conv3x3_k<196, 64, 8, 1><<<dim3(64, 8, NB), blk, 0, stream>>>(
      pin, w1, b1, nullptr, nullptr, hA);
  // conv2: 64 -> 64, leaky
  conv3x3_k<64, 64, 8, 1><<<dim3(64, 8, NB), blk, 0, stream>>>(
      hA, w2, b2, nullptr, nullptr, hB);
  // conv3: 64 -> 64, leaky
  conv3x3_k<64, 64, 8, 1><<<dim3(64, 8, NB), blk, 0, stream>>>(
      hB, w3, b3, nullptr, nullptr, hA);
  // conv4: 64 -> 432, fused offset/mask activation, unpadded out
  conv3x3_k<64, 432, 24, 2><<<dim3(64, 18, NB), blk, 0, stream>>>(
      hA, w4, b4, fl1, fl2, o4);
  // deformable conv
  deform_k<16><<<dim3(64, 4, NB), blk, 0, stream>>>(x, o4, dcn_w, dcn_b,
                                                    (float*)d_out);
}

// Round 8
// 1341.054 us; speedup vs baseline: 1.3046x; 1.3046x over previous
//
#include <hip/hip_runtime.h>
#include <math.h>

namespace {
constexpr int H = 128, W = 128, NB = 2;
constexpr int HW = H * W;
constexpr int WP = 130, HP = 130, HWP = WP * HP;   // padded image
constexpr int NTHR = 256;
constexpr int DG = 16, CPG = 8, DCN_CIN = 128, DCN_COUT = 64;

// workspace layout (floats). Total = 18,350,080 f = 73,400,320 B (proven size).
// hA [0, 2163200) ; hB [2163200, 4326400) ; pin [4326400, 10951200)
// o4 [4194304, 18350080)  -- overlaps pin (dead by conv4) and hB tail (dead by conv4)
// x_t [0, 4194304)        -- written AFTER conv4 (hA/hB dead), read by deform
constexpr size_t OFF_HA  = 0;
constexpr size_t OFF_HB  = 2163200;
constexpr size_t OFF_PIN = 4326400;
constexpr size_t OFF_O4  = 4194304;
constexpr size_t OFF_XT  = 0;
}

// ---------------------------------------------------------------------------
// Prep: pack ef(192)+flow1(2)+flow2(2) -> padded pin interior, and zero the
// 1-px borders of pin, hA, hB (ws is poisoned each call).
// ---------------------------------------------------------------------------
__global__ __launch_bounds__(NTHR) void prep_k(
    const float* __restrict__ ef, const float* __restrict__ f1,
    const float* __restrict__ f2,
    float* __restrict__ pin, float* __restrict__ hA, float* __restrict__ hB)
{
  constexpr int PACK_N  = NB * 196 * HW;          // 6,422,528
  constexpr int BORD_CH = NB * (196 + 64 + 64);   // 648 channels with borders
  constexpr int BORD_N  = BORD_CH * 516;
  const int total = PACK_N + BORD_N;
  for (int gid = blockIdx.x * NTHR + threadIdx.x; gid < total;
       gid += gridDim.x * NTHR) {
    if (gid < PACK_N) {
      const int b = gid / (196 * HW);
      const int r = gid - b * 196 * HW;
      const int c = r / HW;
      const int p = r - c * HW;
      const int y = p / W, x = p - y * W;
      float v;
      if (c < 192)      v = ef[(b * 192 + c) * HW + p];
      else if (c < 194) v = f1[(b * 2 + (c - 192)) * HW + p];
      else              v = f2[(b * 2 + (c - 194)) * HW + p];
      pin[(size_t)(b * 196 + c) * HWP + (y + 1) * WP + (x + 1)] = v;
    } else {
      const int k  = gid - PACK_N;
      const int ch = k / 516;
      const int e  = k - ch * 516;
      float* base;
      if (ch < NB * 196)            base = pin + (size_t)ch * HWP;
      else if (ch < NB * 196 + NB * 64) base = hA + (size_t)(ch - NB * 196) * HWP;
      else                          base = hB + (size_t)(ch - NB * 196 - NB * 64) * HWP;
      int off;
      if (e < 260) { const int rr = (e < 130) ? 0 : (HP - 1); off = rr * WP + (e % 130); }
      else { const int e2 = e - 260; const int y = 1 + (e2 & 127); off = y * WP + ((e2 < 128) ? 0 : (WP - 1)); }
      base[off] = 0.f;
    }
  }
}

// ---------------------------------------------------------------------------
// 3x3 conv, padded input (no bounds checks). Software-pipelined staging:
// global->reg prefetch overlaps compute; regs->LDS next round; 1 barrier/round.
// EPI: 1 = leaky(0.1) -> padded out; 2 = offset/mask activation -> unpadded out.
// ---------------------------------------------------------------------------
template<int CIN, int COUT, int CC, int EPI>
__global__ __launch_bounds__(NTHR) void conv3x3_k(
    const float* __restrict__ in,   // padded [NB][CIN][130][130]
    const float* __restrict__ wt,   // [COUT][CIN][9]
    const float* __restrict__ bias,
    const float* __restrict__ fl1, const float* __restrict__ fl2,
    float* __restrict__ out)
{
  constexpr int NST = 4, HN = 18 * 18, IN_E = NST * HN;     // 1296
  constexpr int J_IN = (IN_E + NTHR - 1) / NTHR;            // 6
  constexpr int WT_E = CC * NST * 9;
  constexpr int J_WT = (WT_E + NTHR - 1) / NTHR;
  constexpr int R = CIN / NST;

  __shared__ float s_in[2][NST * HN];
  __shared__ float s_wt[2][CC * NST * 12];

  const int t    = threadIdx.x;
  const int tile = blockIdx.x;
  const int tx0  = (tile & 7) * 16, ty0 = (tile >> 3) * 16;
  const int oc0  = blockIdx.y * CC;
  const int b    = blockIdx.z;
  const int lx   = t & 15, ly = t >> 4;

  const float* inB = in + (size_t)b * CIN * HWP;

  int iadr[J_IN]; bool ivl[J_IN];
  #pragma unroll
  for (int j = 0; j < J_IN; ++j) {
    const int idx = j * NTHR + t;
    ivl[j] = idx < IN_E;
    const int ii = idx / HN, rem = idx - ii * HN;
    const int hy = rem / 18, hx = rem - hy * 18;
    iadr[j] = ivl[j] ? (ii * HWP + (ty0 + hy) * WP + (tx0 + hx)) : 0;
  }
  int wadr[J_WT], wl[J_WT]; bool wvl[J_WT];
  #pragma unroll
  for (int j = 0; j < J_WT; ++j) {
    const int idx = j * NTHR + t;
    wvl[j] = idx < WT_E;
    const int o = idx / 36, r2 = idx - o * 36, ii = r2 / 9, k = r2 - ii * 9;
    wadr[j] = wvl[j] ? (((oc0 + o) * CIN + ii) * 9 + k) : 0;
    wl[j]   = wvl[j] ? ((o * NST + ii) * 12 + k) : 0;
  }

  float rin[J_IN], rwt[J_WT], acc[CC];
  #pragma unroll
  for (int o = 0; o < CC; ++o) acc[o] = 0.f;

  #pragma unroll
  for (int j = 0; j < J_IN; ++j) if (ivl[j]) rin[j] = inB[iadr[j]];
  #pragma unroll
  for (int j = 0; j < J_WT; ++j) if (wvl[j]) rwt[j] = wt[wadr[j]];

  for (int r = 0; r < R; ++r) {
    float* si = s_in[r & 1];
    float* sw = s_wt[r & 1];
    #pragma unroll
    for (int j = 0; j < J_IN; ++j) if (ivl[j]) si[j * NTHR + t] = rin[j];
    #pragma unroll
    for (int j = 0; j < J_WT; ++j) if (wvl[j]) sw[wl[j]] = rwt[j];
    __syncthreads();
    if (r + 1 < R) {            // async prefetch, in flight during compute
      const float* ip = inB + (size_t)(r + 1) * NST * HWP;
      const float* wp = wt + (size_t)(r + 1) * NST * 9;
      #pragma unroll
      for (int j = 0; j < J_IN; ++j) if (ivl[j]) rin[j] = ip[iadr[j]];
      #pragma unroll
      for (int j = 0; j < J_WT; ++j) if (wvl[j]) rwt[j] = wp[wadr[j]];
    }
    #pragma unroll
    for (int i = 0; i < NST; ++i) {
      float va[9];
      #pragma unroll
      for (int dy = 0; dy < 3; ++dy)
        #pragma unroll
        for (int dx = 0; dx < 3; ++dx)
          va[dy * 3 + dx] = si[i * HN + (ly + dy) * 18 + (lx + dx)];
      #pragma unroll
      for (int o = 0; o < CC; ++o) {
        const float* wr = &sw[(o * NST + i) * 12];
        #pragma unroll
        for (int k = 0; k < 9; ++k) acc[o] = fmaf(va[k], wr[k], acc[o]);
      }
    }
  }

  if (EPI == 2) {
    const int pix = (ty0 + ly) * W + (tx0 + lx);
    float fv[2][2];
    fv[0][0] = fl1[(b * 2 + 1) * HW + pix];
    fv[0][1] = fl1[(b * 2 + 0) * HW + pix];
    fv[1][0] = fl2[(b * 2 + 1) * HW + pix];
    fv[1][1] = fl2[(b * 2 + 0) * HW + pix];
    #pragma unroll
    for (int o = 0; o < CC; ++o) {
      const int oc = oc0 + o;
      float rr = acc[o] + bias[oc];
      if (oc < 288) {
        const int yx = oc & 1;
        const int g  = (oc >> 1) / 9;
        rr = 10.f * tanhf(rr) + fv[g >= 8 ? 1 : 0][yx];
      } else {
        rr = 1.f / (1.f + expf(-rr));
      }
      out[((size_t)b * COUT + oc) * HW + pix] = rr;
    }
  } else {
    #pragma unroll
    for (int o = 0; o < CC; ++o) {
      const int oc = oc0 + o;
      float rr = acc[o] + bias[oc];
      rr = (rr >= 0.f) ? rr : 0.1f * rr;
      out[((size_t)b * COUT + oc) * HWP + (ty0 + ly + 1) * WP + (tx0 + lx + 1)] = rr;
    }
  }
}

// ---------------------------------------------------------------------------
// Transpose x [B][128][HW] -> x_t [B][16][HW][8]  (group-channel interleaved)
// and pre-fill d_out with bias (deform accumulates with atomicAdd).
// ---------------------------------------------------------------------------
__global__ __launch_bounds__(NTHR) void xpose_k(
    const float* __restrict__ x, const float* __restrict__ db,
    float* __restrict__ xt, float* __restrict__ out)
{
  constexpr int XT_N  = NB * DG * HW;        // 524,288 (b,g,pix) items
  constexpr int OUT_N = NB * DCN_COUT * HW;  // 2,097,152 bias fills
  const int total = XT_N + OUT_N;
  for (int gid = blockIdx.x * NTHR + threadIdx.x; gid < total;
       gid += gridDim.x * NTHR) {
    if (gid < XT_N) {
      const int b = gid / (DG * HW);
      const int r = gid - b * DG * HW;
      const int g = r / HW;
      const int p = r - g * HW;
      float4 v0, v1;
      const float* xs = x + ((size_t)(b * DCN_CIN) + g * CPG) * HW + p;
      v0.x = xs[0 * HW]; v0.y = xs[1 * HW]; v0.z = xs[2 * HW]; v0.w = xs[3 * HW];
      v1.x = xs[4 * HW]; v1.y = xs[5 * HW]; v1.z = xs[6 * HW]; v1.w = xs[7 * HW];
      float4* xd = (float4*)(xt + ((size_t)gid) * CPG);
      xd[0] = v0; xd[1] = v1;
    } else {
      const int k  = gid - XT_N;
      const int oc = (k / HW) & (DCN_COUT - 1);
      out[k] = db[oc];
    }
  }
}

// ---------------------------------------------------------------------------
// Modulated deformable conv, group-split: each block sums GPB groups for ALL
// 64 output channels of a 16x16 pixel tile, then atomicAdds the partial into
// out (pre-filled with bias). Gathers use x_t: one corner for 8 channels =
// 2 x dwordx4. Weight reads are wave-uniform -> scalar loads.
// ---------------------------------------------------------------------------
template<int GPB>
__global__ __launch_bounds__(NTHR) void deform_k(
    const float* __restrict__ xt,     // [B][16][HW][8]
    const float* __restrict__ o4,     // [B,432,H,W] activated offset+mask
    const float* __restrict__ dw,     // [64,128,3,3]
    float* __restrict__ out)          // [B,64,H,W] pre-filled with bias
{
  const int t    = threadIdx.x;
  const int tile = blockIdx.x;
  const int gc   = blockIdx.y;        // group chunk
  const int b    = blockIdx.z;
  const int lx   = t & 15, ly = t >> 4;
  const int hx   = (tile & 7) * 16 + lx;
  const int hy   = (tile >> 3) * 16 + ly;
  const int pix  = hy * W + hx;

  const float* ob = o4 + (size_t)(b * 432) * HW + pix;

  float acc[DCN_COUT];
  #pragma unroll
  for (int o = 0; o < DCN_COUT; ++o) acc[o] = 0.f;

  #pragma unroll 1
  for (int gi = 0; gi < GPB; ++gi) {
    const int g = gc * GPB + gi;
    const float* xg = xt + ((size_t)(b * DG + g)) * HW * CPG;

    #pragma unroll 1
    for (int k = 0; k < 9; ++k) {
      const int cb = g * 9 + k;
      const float oy = ob[(2 * cb + 0) * HW];
      const float ox = ob[(2 * cb + 1) * HW];
      const float mk = ob[(288 + cb) * HW];
      const float py  = (float)(hy + k / 3 - 1) + oy;
      const float pxx = (float)(hx + k % 3 - 1) + ox;
      const float y0f = floorf(py), x0f = floorf(pxx);
      const float wy = py - y0f, wx = pxx - x0f;
      const int y0 = (int)y0f, x0 = (int)x0f;
      const bool vy0 = (y0 >= 0) && (y0 < H);
      const bool vy1 = (y0 + 1 >= 0) && (y0 + 1 < H);
      const bool vx0 = (x0 >= 0) && (x0 < W);
      const bool vx1 = (x0 + 1 >= 0) && (x0 + 1 < W);
      const int cy0 = min(max(y0, 0), H - 1);
      const int cy1 = min(max(y0 + 1, 0), H - 1);
      const int cx0 = min(max(x0, 0), W - 1);
      const int cx1 = min(max(x0 + 1, 0), W - 1);
      const float w00 = (vy0 && vx0) ? (1.f - wy) * (1.f - wx) * mk : 0.f;
      const float w01 = (vy0 && vx1) ? (1.f - wy) * wx * mk : 0.f;
      const float w10 = (vy1 && vx0) ? wy * (1.f - wx) * mk : 0.f;
      const float w11 = (vy1 && vx1) ? wy * wx * mk : 0.f;

      const float4* p00 = (const float4*)(xg + (size_t)(cy0 * W + cx0) * CPG);
      const float4* p01 = (const float4*)(xg + (size_t)(cy0 * W + cx1) * CPG);
      const float4* p10 = (const float4*)(xg + (size_t)(cy1 * W + cx0) * CPG);
      const float4* p11 = (const float4*)(xg + (size_t)(cy1 * W + cx1) * CPG);
      const float4 a0 = p00[0], a1 = p00[1];
      const float4 b0 = p01[0], b1 = p01[1];
      const float4 c0 = p10[0], c1 = p10[1];
      const float4 d0 = p11[0], d1 = p11[1];

      float val[CPG];
      val[0] = fmaf(w00, a0.x, fmaf(w01, b0.x, fmaf(w10, c0.x, w11 * d0.x)));
      val[1] = fmaf(w00, a0.y, fmaf(w01, b0.y, fmaf(w10, c0.y, w11 * d0.y)));
      val[2] = fmaf(w00, a0.z, fmaf(w01, b0.z, fmaf(w10, c0.z, w11 * d0.z)));
      val[3] = fmaf(w00, a0.w, fmaf(w01, b0.w, fmaf(w10, c0.w, w11 * d0.w)));
      val[4] = fmaf(w00, a1.x, fmaf(w01, b1.x, fmaf(w10, c1.x, w11 * d1.x)));
      val[5] = fmaf(w00, a1.y, fmaf(w01, b1.y, fmaf(w10, c1.y, w11 * d1.y)));
      val[6] = fmaf(w00, a1.z, fmaf(w01, b1.z, fmaf(w10, c1.z, w11 * d1.z)));
      val[7] = fmaf(w00, a1.w, fmaf(w01, b1.w, fmaf(w10, c1.w, w11 * d1.w)));

      #pragma unroll
      for (int c = 0; c < CPG; ++c) {
        const float* wp = dw + (size_t)((g * CPG + c) * 9 + k);  // + o*1152
        #pragma unroll
        for (int o = 0; o < DCN_COUT; ++o)
          acc[o] = fmaf(val[c], wp[(size_t)o * (DCN_CIN * 9)], acc[o]);
      }
    }
  }

  float* ot = out + (size_t)(b * DCN_COUT) * HW + pix;
  #pragma unroll
  for (int o = 0; o < DCN_COUT; ++o)
    atomicAdd(ot + (size_t)o * HW, acc[o]);
}

// ---------------------------------------------------------------------------
extern "C" void kernel_launch(void* const* d_in, const int* in_sizes, int n_in,
                              void* d_out, int out_size, void* d_ws, size_t ws_size,
                              hipStream_t stream) {
  const float* x     = (const float*)d_in[0];
  const float* ef    = (const float*)d_in[1];
  const float* fl1   = (const float*)d_in[2];
  const float* fl2   = (const float*)d_in[3];
  const float* w1    = (const float*)d_in[4];
  const float* b1    = (const float*)d_in[5];
  const float* w2    = (const float*)d_in[6];
  const float* b2    = (const float*)d_in[7];
  const float* w3    = (const float*)d_in[8];
  const float* b3    = (const float*)d_in[9];
  const float* w4    = (const float*)d_in[10];
  const float* b4    = (const float*)d_in[11];
  const float* dcn_w = (const float*)d_in[12];
  const float* dcn_b = (const float*)d_in[13];

  float* ws  = (float*)d_ws;
  float* hA  = ws + OFF_HA;
  float* hB  = ws + OFF_HB;
  float* pin = ws + OFF_PIN;
  float* o4  = ws + OFF_O4;
  float* xt  = ws + OFF_XT;     // written after conv4 (hA/hB dead)

  const dim3 blk(NTHR);
  prep_k<<<2048, blk, 0, stream>>>(ef, fl1, fl2, pin, hA, hB);
  // conv1: 196 -> 64, leaky
  conv3x3_k<196, 64, 8, 1><<<dim3(64, 8, NB), blk, 0, stream>>>(
      pin, w1, b1, nullptr, nullptr, hA);
  // conv2: 64 -> 64, leaky
  conv3x3_k<64, 64, 8, 1><<<dim3(64, 8, NB), blk, 0, stream>>>(
      hA, w2, b2, nullptr, nullptr, hB);
  // conv3: 64 -> 64, leaky
  conv3x3_k<64, 64, 8, 1><<<dim3(64, 8, NB), blk, 0, stream>>>(
      hB, w3, b3, nullptr, nullptr, hA);
  // conv4: 64 -> 432, fused offset/mask activation, unpadded out
  conv3x3_k<64, 432, 24, 2><<<dim3(64, 18, NB), blk, 0, stream>>>(
      hA, w4, b4, fl1, fl2, o4);
  // transpose x for vectorized gathers + pre-fill out with bias
  xpose_k<<<2048, blk, 0, stream>>>(x, dcn_b, xt, (float*)d_out);
  // deformable conv: 8 group-chunks x 2 groups, atomic accumulate
  deform_k<2><<<dim3(64, 8, NB), blk, 0, stream>>>(xt, o4, dcn_w,
                                                   (float*)d_out);
}

// Round 9
// 1009.412 us; speedup vs baseline: 1.7333x; 1.3286x over previous
//
#include <hip/hip_runtime.h>
#include <math.h>

namespace {
constexpr int H = 128, W = 128, NB = 2;
constexpr int HW = H * W;
constexpr int WP = 130, HP = 130, HWP = WP * HP;   // padded image
constexpr int NTHR = 256;
constexpr int DG = 16, CPG = 8, DCN_CIN = 128, DCN_COUT = 64;

// workspace layout (floats). Total = 18,350,080 f = 73,400,320 B (proven size).
constexpr size_t OFF_HA  = 0;
constexpr size_t OFF_HB  = 2163200;
constexpr size_t OFF_PIN = 4326400;
constexpr size_t OFF_O4  = 4194304;
constexpr size_t OFF_XT  = 0;
}

// ---------------------------------------------------------------------------
// Prep: pack ef(192)+flow1(2)+flow2(2) -> padded pin interior, and zero the
// 1-px borders of pin, hA, hB (ws is poisoned each call).
// ---------------------------------------------------------------------------
__global__ __launch_bounds__(NTHR) void prep_k(
    const float* __restrict__ ef, const float* __restrict__ f1,
    const float* __restrict__ f2,
    float* __restrict__ pin, float* __restrict__ hA, float* __restrict__ hB)
{
  constexpr int PACK_N  = NB * 196 * HW;          // 6,422,528
  constexpr int BORD_CH = NB * (196 + 64 + 64);   // 648 channels with borders
  constexpr int BORD_N  = BORD_CH * 516;
  const int total = PACK_N + BORD_N;
  for (int gid = blockIdx.x * NTHR + threadIdx.x; gid < total;
       gid += gridDim.x * NTHR) {
    if (gid < PACK_N) {
      const int b = gid / (196 * HW);
      const int r = gid - b * 196 * HW;
      const int c = r / HW;
      const int p = r - c * HW;
      const int y = p / W, x = p - y * W;
      float v;
      if (c < 192)      v = ef[(b * 192 + c) * HW + p];
      else if (c < 194) v = f1[(b * 2 + (c - 192)) * HW + p];
      else              v = f2[(b * 2 + (c - 194)) * HW + p];
      pin[(size_t)(b * 196 + c) * HWP + (y + 1) * WP + (x + 1)] = v;
    } else {
      const int k  = gid - PACK_N;
      const int ch = k / 516;
      const int e  = k - ch * 516;
      float* base;
      if (ch < NB * 196)            base = pin + (size_t)ch * HWP;
      else if (ch < NB * 196 + NB * 64) base = hA + (size_t)(ch - NB * 196) * HWP;
      else                          base = hB + (size_t)(ch - NB * 196 - NB * 64) * HWP;
      int off;
      if (e < 260) { const int rr = (e < 130) ? 0 : (HP - 1); off = rr * WP + (e % 130); }
      else { const int e2 = e - 260; const int y = 1 + (e2 & 127); off = y * WP + ((e2 < 128) ? 0 : (WP - 1)); }
      base[off] = 0.f;
    }
  }
}

// ---------------------------------------------------------------------------
// 3x3 conv, padded input. 32x32 px tile, each thread a 2x2 pixel patch:
// one 4x4 input window feeds 4 outputs -> weight LDS reads amortized 4x
// (round-8 counters: conv was LDS-issue-bound on per-FMA weight reads).
// Software-pipelined staging, 1 barrier/round, double-buffered LDS.
// EPI: 1 = leaky(0.1) -> padded out; 2 = offset/mask activation -> unpadded.
// ---------------------------------------------------------------------------
template<int CIN, int COUT, int CC, int EPI>
__global__ __launch_bounds__(NTHR) void conv3x3_k(
    const float* __restrict__ in,   // padded [NB][CIN][130][130]
    const float* __restrict__ wt,   // [COUT][CIN][9]
    const float* __restrict__ bias,
    const float* __restrict__ fl1, const float* __restrict__ fl2,
    float* __restrict__ out)
{
  constexpr int NST = 2;
  constexpr int HHW = 34, HN = HHW * HHW;          // 34x34 halo = 1156
  constexpr int IN_E = NST * HN;                   // 2312
  constexpr int J_IN = (IN_E + NTHR - 1) / NTHR;   // 10
  constexpr int WT_E = CC * NST * 9;
  constexpr int J_WT = (WT_E + NTHR - 1) / NTHR;
  constexpr int R = CIN / NST;

  __shared__ float s_in[2][NST * HN];
  __shared__ float s_wt[2][CC * NST * 12];

  const int t    = threadIdx.x;
  const int tile = blockIdx.x;                     // 16 tiles (4x4 of 32x32)
  const int tx0  = (tile & 3) * 32, ty0 = (tile >> 2) * 32;
  const int oc0  = blockIdx.y * CC;
  const int b    = blockIdx.z;
  const int px0  = (t & 15) * 2;                   // 2x2 patch base in tile
  const int py0  = (t >> 4) * 2;

  const float* inB = in + (size_t)b * CIN * HWP;

  int iadr[J_IN]; bool ivl[J_IN];
  #pragma unroll
  for (int j = 0; j < J_IN; ++j) {
    const int idx = j * NTHR + t;
    ivl[j] = idx < IN_E;
    const int ii = idx / HN, rem = idx - ii * HN;
    const int hy = rem / HHW, hx = rem - hy * HHW;
    iadr[j] = ivl[j] ? (ii * HWP + (ty0 + hy) * WP + (tx0 + hx)) : 0;
  }
  int wadr[J_WT], wl[J_WT]; bool wvl[J_WT];
  #pragma unroll
  for (int j = 0; j < J_WT; ++j) {
    const int idx = j * NTHR + t;
    wvl[j] = idx < WT_E;
    const int o = idx / (NST * 9), r2 = idx - o * (NST * 9), ii = r2 / 9, k = r2 - ii * 9;
    wadr[j] = wvl[j] ? (((oc0 + o) * CIN + ii) * 9 + k) : 0;
    wl[j]   = wvl[j] ? ((o * NST + ii) * 12 + k) : 0;
  }

  float rin[J_IN], rwt[J_WT], acc[CC][4];
  #pragma unroll
  for (int o = 0; o < CC; ++o)
    #pragma unroll
    for (int p = 0; p < 4; ++p) acc[o][p] = 0.f;

  #pragma unroll
  for (int j = 0; j < J_IN; ++j) if (ivl[j]) rin[j] = inB[iadr[j]];
  #pragma unroll
  for (int j = 0; j < J_WT; ++j) if (wvl[j]) rwt[j] = wt[wadr[j]];

  for (int r = 0; r < R; ++r) {
    float* si = s_in[r & 1];
    float* sw = s_wt[r & 1];
    #pragma unroll
    for (int j = 0; j < J_IN; ++j) if (ivl[j]) si[j * NTHR + t] = rin[j];
    #pragma unroll
    for (int j = 0; j < J_WT; ++j) if (wvl[j]) sw[wl[j]] = rwt[j];
    __syncthreads();
    if (r + 1 < R) {            // prefetch next round, in flight during compute
      const float* ip = inB + (size_t)(r + 1) * NST * HWP;
      const float* wp = wt + (size_t)(r + 1) * NST * 9;
      #pragma unroll
      for (int j = 0; j < J_IN; ++j) if (ivl[j]) rin[j] = ip[iadr[j]];
      #pragma unroll
      for (int j = 0; j < J_WT; ++j) if (wvl[j]) rwt[j] = wp[wadr[j]];
    }
    #pragma unroll
    for (int i = 0; i < NST; ++i) {
      float va[16];
      #pragma unroll
      for (int dy = 0; dy < 4; ++dy)
        #pragma unroll
        for (int dx = 0; dx < 4; ++dx)
          va[dy * 4 + dx] = si[i * HN + (py0 + dy) * HHW + (px0 + dx)];
      #pragma unroll
      for (int o = 0; o < CC; ++o) {
        const float* wr = &sw[(o * NST + i) * 12];
        float w[9];
        #pragma unroll
        for (int k = 0; k < 9; ++k) w[k] = wr[k];
        #pragma unroll
        for (int py = 0; py < 2; ++py)
          #pragma unroll
          for (int px = 0; px < 2; ++px) {
            float a = acc[o][py * 2 + px];
            #pragma unroll
            for (int ky = 0; ky < 3; ++ky)
              #pragma unroll
              for (int kx = 0; kx < 3; ++kx)
                a = fmaf(va[(py + ky) * 4 + (px + kx)], w[ky * 3 + kx], a);
            acc[o][py * 2 + px] = a;
          }
      }
    }
  }

  if (EPI == 2) {
    // per-pixel flow addends: flo[sel][yx][py][px]
    float flo[2][2][2][2];
    #pragma unroll
    for (int py = 0; py < 2; ++py)
      #pragma unroll
      for (int px = 0; px < 2; ++px) {
        const int pix = (ty0 + py0 + py) * W + (tx0 + px0 + px);
        flo[0][0][py][px] = fl1[(b * 2 + 1) * HW + pix];
        flo[0][1][py][px] = fl1[(b * 2 + 0) * HW + pix];
        flo[1][0][py][px] = fl2[(b * 2 + 1) * HW + pix];
        flo[1][1][py][px] = fl2[(b * 2 + 0) * HW + pix];
      }
    #pragma unroll
    for (int o = 0; o < CC; ++o) {
      const int oc = oc0 + o;
      const float bz = bias[oc];
      const int yx = oc & 1;
      const int sel = ((oc >> 1) / 9 >= 8) ? 1 : 0;
      #pragma unroll
      for (int py = 0; py < 2; ++py)
        #pragma unroll
        for (int px = 0; px < 2; ++px) {
          float rr = acc[o][py * 2 + px] + bz;
          if (oc < 288) rr = 10.f * tanhf(rr) + flo[sel][yx][py][px];
          else          rr = 1.f / (1.f + expf(-rr));
          const int pix = (ty0 + py0 + py) * W + (tx0 + px0 + px);
          out[((size_t)b * COUT + oc) * HW + pix] = rr;
        }
    }
  } else {
    #pragma unroll
    for (int o = 0; o < CC; ++o) {
      const int oc = oc0 + o;
      const float bz = bias[oc];
      #pragma unroll
      for (int py = 0; py < 2; ++py)
        #pragma unroll
        for (int px = 0; px < 2; ++px) {
          float rr = acc[o][py * 2 + px] + bz;
          rr = (rr >= 0.f) ? rr : 0.1f * rr;
          const int y = ty0 + py0 + py, x = tx0 + px0 + px;
          out[((size_t)b * COUT + oc) * HWP + (y + 1) * WP + (x + 1)] = rr;
        }
    }
  }
}

// ---------------------------------------------------------------------------
// Transpose x [B][128][HW] -> x_t [B][16][HW][8]  (group-channel interleaved)
// and pre-fill d_out with bias (deform accumulates with atomicAdd).
// ---------------------------------------------------------------------------
__global__ __launch_bounds__(NTHR) void xpose_k(
    const float* __restrict__ x, const float* __restrict__ db,
    float* __restrict__ xt, float* __restrict__ out)
{
  constexpr int XT_N  = NB * DG * HW;        // 524,288 (b,g,pix) items
  constexpr int OUT_N = NB * DCN_COUT * HW;  // 2,097,152 bias fills
  const int total = XT_N + OUT_N;
  for (int gid = blockIdx.x * NTHR + threadIdx.x; gid < total;
       gid += gridDim.x * NTHR) {
    if (gid < XT_N) {
      const int b = gid / (DG * HW);
      const int r = gid - b * DG * HW;
      const int g = r / HW;
      const int p = r - g * HW;
      float4 v0, v1;
      const float* xs = x + ((size_t)(b * DCN_CIN) + g * CPG) * HW + p;
      v0.x = xs[0 * HW]; v0.y = xs[1 * HW]; v0.z = xs[2 * HW]; v0.w = xs[3 * HW];
      v1.x = xs[4 * HW]; v1.y = xs[5 * HW]; v1.z = xs[6 * HW]; v1.w = xs[7 * HW];
      float4* xd = (float4*)(xt + ((size_t)gid) * CPG);
      xd[0] = v0; xd[1] = v1;
    } else {
      const int k  = gid - XT_N;
      const int oc = (k / HW) & (DCN_COUT - 1);
      out[k] = db[oc];
    }
  }
}

// ---------------------------------------------------------------------------
// Modulated deformable conv, group-split: each block sums GPB groups for ALL
// 64 output channels of a 16x16 pixel tile, then atomicAdds the partial into
// out (pre-filled with bias). Gathers use x_t: one corner for 8 channels =
// 2 x dwordx4. Weight reads are wave-uniform -> scalar loads.
// ---------------------------------------------------------------------------
template<int GPB>
__global__ __launch_bounds__(NTHR) void deform_k(
    const float* __restrict__ xt,     // [B][16][HW][8]
    const float* __restrict__ o4,     // [B,432,H,W] activated offset+mask
    const float* __restrict__ dw,     // [64,128,3,3]
    float* __restrict__ out)          // [B,64,H,W] pre-filled with bias
{
  const int t    = threadIdx.x;
  const int tile = blockIdx.x;
  const int gc   = blockIdx.y;        // group chunk
  const int b    = blockIdx.z;
  const int lx   = t & 15, ly = t >> 4;
  const int hx   = (tile & 7) * 16 + lx;
  const int hy   = (tile >> 3) * 16 + ly;
  const int pix  = hy * W + hx;

  const float* ob = o4 + (size_t)(b * 432) * HW + pix;

  float acc[DCN_COUT];
  #pragma unroll
  for (int o = 0; o < DCN_COUT; ++o) acc[o] = 0.f;

  #pragma unroll 1
  for (int gi = 0; gi < GPB; ++gi) {
    const int g = gc * GPB + gi;
    const float* xg = xt + ((size_t)(b * DG + g)) * HW * CPG;

    #pragma unroll 1
    for (int k = 0; k < 9; ++k) {
      const int cb = g * 9 + k;
      const float oy = ob[(2 * cb + 0) * HW];
      const float ox = ob[(2 * cb + 1) * HW];
      const float mk = ob[(288 + cb) * HW];
      const float py  = (float)(hy + k / 3 - 1) + oy;
      const float pxx = (float)(hx + k % 3 - 1) + ox;
      const float y0f = floorf(py), x0f = floorf(pxx);
      const float wy = py - y0f, wx = pxx - x0f;
      const int y0 = (int)y0f, x0 = (int)x0f;
      const bool vy0 = (y0 >= 0) && (y0 < H);
      const bool vy1 = (y0 + 1 >= 0) && (y0 + 1 < H);
      const bool vx0 = (x0 >= 0) && (x0 < W);
      const bool vx1 = (x0 + 1 >= 0) && (x0 + 1 < W);
      const int cy0 = min(max(y0, 0), H - 1);
      const int cy1 = min(max(y0 + 1, 0), H - 1);
      const int cx0 = min(max(x0, 0), W - 1);
      const int cx1 = min(max(x0 + 1, 0), W - 1);
      const float w00 = (vy0 && vx0) ? (1.f - wy) * (1.f - wx) * mk : 0.f;
      const float w01 = (vy0 && vx1) ? (1.f - wy) * wx * mk : 0.f;
      const float w10 = (vy1 && vx0) ? wy * (1.f - wx) * mk : 0.f;
      const float w11 = (vy1 && vx1) ? wy * wx * mk : 0.f;

      const float4* p00 = (const float4*)(xg + (size_t)(cy0 * W + cx0) * CPG);
      const float4* p01 = (const float4*)(xg + (size_t)(cy0 * W + cx1) * CPG);
      const float4* p10 = (const float4*)(xg + (size_t)(cy1 * W + cx0) * CPG);
      const float4* p11 = (const float4*)(xg + (size_t)(cy1 * W + cx1) * CPG);
      const float4 a0 = p00[0], a1 = p00[1];
      const float4 b0 = p01[0], b1 = p01[1];
      const float4 c0 = p10[0], c1 = p10[1];
      const float4 d0 = p11[0], d1 = p11[1];

      float val[CPG];
      val[0] = fmaf(w00, a0.x, fmaf(w01, b0.x, fmaf(w10, c0.x, w11 * d0.x)));
      val[1] = fmaf(w00, a0.y, fmaf(w01, b0.y, fmaf(w10, c0.y, w11 * d0.y)));
      val[2] = fmaf(w00, a0.z, fmaf(w01, b0.z, fmaf(w10, c0.z, w11 * d0.z)));
      val[3] = fmaf(w00, a0.w, fmaf(w01, b0.w, fmaf(w10, c0.w, w11 * d0.w)));
      val[4] = fmaf(w00, a1.x, fmaf(w01, b1.x, fmaf(w10, c1.x, w11 * d1.x)));
      val[5] = fmaf(w00, a1.y, fmaf(w01, b1.y, fmaf(w10, c1.y, w11 * d1.y)));
      val[6] = fmaf(w00, a1.z, fmaf(w01, b1.z, fmaf(w10, c1.z, w11 * d1.z)));
      val[7] = fmaf(w00, a1.w, fmaf(w01, b1.w, fmaf(w10, c1.w, w11 * d1.w)));

      #pragma unroll
      for (int c = 0; c < CPG; ++c) {
        const float* wp = dw + (size_t)((g * CPG + c) * 9 + k);  // + o*1152
        #pragma unroll
        for (int o = 0; o < DCN_COUT; ++o)
          acc[o] = fmaf(val[c], wp[(size_t)o * (DCN_CIN * 9)], acc[o]);
      }
    }
  }

  float* ot = out + (size_t)(b * DCN_COUT) * HW + pix;
  #pragma unroll
  for (int o = 0; o < DCN_COUT; ++o)
    atomicAdd(ot + (size_t)o * HW, acc[o]);
}

// ---------------------------------------------------------------------------
extern "C" void kernel_launch(void* const* d_in, const int* in_sizes, int n_in,
                              void* d_out, int out_size, void* d_ws, size_t ws_size,
                              hipStream_t stream) {
  const float* x     = (const float*)d_in[0];
  const float* ef    = (const float*)d_in[1];
  const float* fl1   = (const float*)d_in[2];
  const float* fl2   = (const float*)d_in[3];
  const float* w1    = (const float*)d_in[4];
  const float* b1    = (const float*)d_in[5];
  const float* w2    = (const float*)d_in[6];
  const float* b2    = (const float*)d_in[7];
  const float* w3    = (const float*)d_in[8];
  const float* b3    = (const float*)d_in[9];
  const float* w4    = (const float*)d_in[10];
  const float* b4    = (const float*)d_in[11];
  const float* dcn_w = (const float*)d_in[12];
  const float* dcn_b = (const float*)d_in[13];

  float* ws  = (float*)d_ws;
  float* hA  = ws + OFF_HA;
  float* hB  = ws + OFF_HB;
  float* pin = ws + OFF_PIN;
  float* o4  = ws + OFF_O4;
  float* xt  = ws + OFF_XT;     // written after conv4 (hA/hB dead)

  const dim3 blk(NTHR);
  prep_k<<<2048, blk, 0, stream>>>(ef, fl1, fl2, pin, hA, hB);
  // conv1: 196 -> 64, leaky.  32x32 tiles, CC=4 -> 512 blocks
  conv3x3_k<196, 64, 4, 1><<<dim3(16, 16, NB), blk, 0, stream>>>(
      pin, w1, b1, nullptr, nullptr, hA);
  // conv2: 64 -> 64, leaky
  conv3x3_k<64, 64, 4, 1><<<dim3(16, 16, NB), blk, 0, stream>>>(
      hA, w2, b2, nullptr, nullptr, hB);
  // conv3: 64 -> 64, leaky
  conv3x3_k<64, 64, 4, 1><<<dim3(16, 16, NB), blk, 0, stream>>>(
      hB, w3, b3, nullptr, nullptr, hA);
  // conv4: 64 -> 432, fused offset/mask activation.  CC=16 -> 864 blocks
  conv3x3_k<64, 432, 16, 2><<<dim3(16, 27, NB), blk, 0, stream>>>(
      hA, w4, b4, fl1, fl2, o4);
  // transpose x for vectorized gathers + pre-fill out with bias
  xpose_k<<<2048, blk, 0, stream>>>(x, dcn_b, xt, (float*)d_out);
  // deformable conv: 8 group-chunks x 2 groups, atomic accumulate
  deform_k<2><<<dim3(64, 8, NB), blk, 0, stream>>>(xt, o4, dcn_w,
                                                   (float*)d_out);
}

// Round 10
// 873.204 us; speedup vs baseline: 2.0036x; 1.1560x over previous
//
#include <hip/hip_runtime.h>
#include <math.h>

namespace {
constexpr int H = 128, W = 128, NB = 2;
constexpr int HW = H * W;
constexpr int WP = 130, HP = 130, HWP = WP * HP;   // padded image
constexpr int NTHR = 256;
constexpr int DG = 16, CPG = 8, DCN_CIN = 128, DCN_COUT = 64;

// workspace layout (floats). Total = 18,350,080 f = 73,400,320 B (proven size).
constexpr size_t OFF_HA  = 0;
constexpr size_t OFF_HB  = 2163200;
constexpr size_t OFF_PIN = 4326400;
constexpr size_t OFF_O4  = 4194304;
constexpr size_t OFF_XT  = 0;
}

// ---------------------------------------------------------------------------
// Prep: pack ef(192)+flow1(2)+flow2(2) -> padded pin interior, and zero the
// 1-px borders of pin, hA, hB (ws is poisoned each call).
// ---------------------------------------------------------------------------
__global__ __launch_bounds__(NTHR) void prep_k(
    const float* __restrict__ ef, const float* __restrict__ f1,
    const float* __restrict__ f2,
    float* __restrict__ pin, float* __restrict__ hA, float* __restrict__ hB)
{
  constexpr int PACK_N  = NB * 196 * HW;          // 6,422,528
  constexpr int BORD_CH = NB * (196 + 64 + 64);   // 648 channels with borders
  constexpr int BORD_N  = BORD_CH * 516;
  const int total = PACK_N + BORD_N;
  for (int gid = blockIdx.x * NTHR + threadIdx.x; gid < total;
       gid += gridDim.x * NTHR) {
    if (gid < PACK_N) {
      const int b = gid / (196 * HW);
      const int r = gid - b * 196 * HW;
      const int c = r / HW;
      const int p = r - c * HW;
      const int y = p / W, x = p - y * W;
      float v;
      if (c < 192)      v = ef[(b * 192 + c) * HW + p];
      else if (c < 194) v = f1[(b * 2 + (c - 192)) * HW + p];
      else              v = f2[(b * 2 + (c - 194)) * HW + p];
      pin[(size_t)(b * 196 + c) * HWP + (y + 1) * WP + (x + 1)] = v;
    } else {
      const int k  = gid - PACK_N;
      const int ch = k / 516;
      const int e  = k - ch * 516;
      float* base;
      if (ch < NB * 196)            base = pin + (size_t)ch * HWP;
      else if (ch < NB * 196 + NB * 64) base = hA + (size_t)(ch - NB * 196) * HWP;
      else                          base = hB + (size_t)(ch - NB * 196 - NB * 64) * HWP;
      int off;
      if (e < 260) { const int rr = (e < 130) ? 0 : (HP - 1); off = rr * WP + (e % 130); }
      else { const int e2 = e - 260; const int y = 1 + (e2 & 127); off = y * WP + ((e2 < 128) ? 0 : (WP - 1)); }
      base[off] = 0.f;
    }
  }
}

// ---------------------------------------------------------------------------
// 3x3 conv, padded input. 32x32 px tile, each thread a 2x2 pixel patch:
// one 4x4 input window feeds 4 outputs -> weight LDS reads amortized 4x.
// Software-pipelined staging, 1 barrier/round, double-buffered LDS.
// EPI: 1 = leaky(0.1) -> padded out; 2 = offset/mask activation -> unpadded.
// ---------------------------------------------------------------------------
template<int CIN, int COUT, int CC, int EPI>
__global__ __launch_bounds__(NTHR) void conv3x3_k(
    const float* __restrict__ in,   // padded [NB][CIN][130][130]
    const float* __restrict__ wt,   // [COUT][CIN][9]
    const float* __restrict__ bias,
    const float* __restrict__ fl1, const float* __restrict__ fl2,
    float* __restrict__ out)
{
  constexpr int NST = 2;
  constexpr int HHW = 34, HN = HHW * HHW;          // 34x34 halo = 1156
  constexpr int IN_E = NST * HN;                   // 2312
  constexpr int J_IN = (IN_E + NTHR - 1) / NTHR;   // 10
  constexpr int WT_E = CC * NST * 9;
  constexpr int J_WT = (WT_E + NTHR - 1) / NTHR;
  constexpr int R = CIN / NST;

  __shared__ float s_in[2][NST * HN];
  __shared__ float s_wt[2][CC * NST * 12];

  const int t    = threadIdx.x;
  const int tile = blockIdx.x;                     // 16 tiles (4x4 of 32x32)
  const int tx0  = (tile & 3) * 32, ty0 = (tile >> 2) * 32;
  const int oc0  = blockIdx.y * CC;
  const int b    = blockIdx.z;
  const int px0  = (t & 15) * 2;                   // 2x2 patch base in tile
  const int py0  = (t >> 4) * 2;

  const float* inB = in + (size_t)b * CIN * HWP;

  int iadr[J_IN]; bool ivl[J_IN];
  #pragma unroll
  for (int j = 0; j < J_IN; ++j) {
    const int idx = j * NTHR + t;
    ivl[j] = idx < IN_E;
    const int ii = idx / HN, rem = idx - ii * HN;
    const int hy = rem / HHW, hx = rem - hy * HHW;
    iadr[j] = ivl[j] ? (ii * HWP + (ty0 + hy) * WP + (tx0 + hx)) : 0;
  }
  int wadr[J_WT], wl[J_WT]; bool wvl[J_WT];
  #pragma unroll
  for (int j = 0; j < J_WT; ++j) {
    const int idx = j * NTHR + t;
    wvl[j] = idx < WT_E;
    const int o = idx / (NST * 9), r2 = idx - o * (NST * 9), ii = r2 / 9, k = r2 - ii * 9;
    wadr[j] = wvl[j] ? (((oc0 + o) * CIN + ii) * 9 + k) : 0;
    wl[j]   = wvl[j] ? ((o * NST + ii) * 12 + k) : 0;
  }

  float rin[J_IN], rwt[J_WT], acc[CC][4];
  #pragma unroll
  for (int o = 0; o < CC; ++o)
    #pragma unroll
    for (int p = 0; p < 4; ++p) acc[o][p] = 0.f;

  #pragma unroll
  for (int j = 0; j < J_IN; ++j) if (ivl[j]) rin[j] = inB[iadr[j]];
  #pragma unroll
  for (int j = 0; j < J_WT; ++j) if (wvl[j]) rwt[j] = wt[wadr[j]];

  for (int r = 0; r < R; ++r) {
    float* si = s_in[r & 1];
    float* sw = s_wt[r & 1];
    #pragma unroll
    for (int j = 0; j < J_IN; ++j) if (ivl[j]) si[j * NTHR + t] = rin[j];
    #pragma unroll
    for (int j = 0; j < J_WT; ++j) if (wvl[j]) sw[wl[j]] = rwt[j];
    __syncthreads();
    if (r + 1 < R) {            // prefetch next round, in flight during compute
      const float* ip = inB + (size_t)(r + 1) * NST * HWP;
      const float* wp = wt + (size_t)(r + 1) * NST * 9;
      #pragma unroll
      for (int j = 0; j < J_IN; ++j) if (ivl[j]) rin[j] = ip[iadr[j]];
      #pragma unroll
      for (int j = 0; j < J_WT; ++j) if (wvl[j]) rwt[j] = wp[wadr[j]];
    }
    #pragma unroll
    for (int i = 0; i < NST; ++i) {
      float va[16];
      #pragma unroll
      for (int dy = 0; dy < 4; ++dy)
        #pragma unroll
        for (int dx = 0; dx < 4; ++dx)
          va[dy * 4 + dx] = si[i * HN + (py0 + dy) * HHW + (px0 + dx)];
      #pragma unroll
      for (int o = 0; o < CC; ++o) {
        const float* wr = &sw[(o * NST + i) * 12];
        float w[9];
        #pragma unroll
        for (int k = 0; k < 9; ++k) w[k] = wr[k];
        #pragma unroll
        for (int py = 0; py < 2; ++py)
          #pragma unroll
          for (int px = 0; px < 2; ++px) {
            float a = acc[o][py * 2 + px];
            #pragma unroll
            for (int ky = 0; ky < 3; ++ky)
              #pragma unroll
              for (int kx = 0; kx < 3; ++kx)
                a = fmaf(va[(py + ky) * 4 + (px + kx)], w[ky * 3 + kx], a);
            acc[o][py * 2 + px] = a;
          }
      }
    }
  }

  if (EPI == 2) {
    // per-pixel flow addends: flo[sel][yx][py][px]
    float flo[2][2][2][2];
    #pragma unroll
    for (int py = 0; py < 2; ++py)
      #pragma unroll
      for (int px = 0; px < 2; ++px) {
        const int pix = (ty0 + py0 + py) * W + (tx0 + px0 + px);
        flo[0][0][py][px] = fl1[(b * 2 + 1) * HW + pix];
        flo[0][1][py][px] = fl1[(b * 2 + 0) * HW + pix];
        flo[1][0][py][px] = fl2[(b * 2 + 1) * HW + pix];
        flo[1][1][py][px] = fl2[(b * 2 + 0) * HW + pix];
      }
    #pragma unroll
    for (int o = 0; o < CC; ++o) {
      const int oc = oc0 + o;
      const float bz = bias[oc];
      const int yx = oc & 1;
      const int sel = ((oc >> 1) / 9 >= 8) ? 1 : 0;
      #pragma unroll
      for (int py = 0; py < 2; ++py)
        #pragma unroll
        for (int px = 0; px < 2; ++px) {
          float rr = acc[o][py * 2 + px] + bz;
          if (oc < 288) rr = 10.f * tanhf(rr) + flo[sel][yx][py][px];
          else          rr = 1.f / (1.f + expf(-rr));
          const int pix = (ty0 + py0 + py) * W + (tx0 + px0 + px);
          out[((size_t)b * COUT + oc) * HW + pix] = rr;
        }
    }
  } else {
    #pragma unroll
    for (int o = 0; o < CC; ++o) {
      const int oc = oc0 + o;
      const float bz = bias[oc];
      #pragma unroll
      for (int py = 0; py < 2; ++py)
        #pragma unroll
        for (int px = 0; px < 2; ++px) {
          float rr = acc[o][py * 2 + px] + bz;
          rr = (rr >= 0.f) ? rr : 0.1f * rr;
          const int y = ty0 + py0 + py, x = tx0 + px0 + px;
          out[((size_t)b * COUT + oc) * HWP + (y + 1) * WP + (x + 1)] = rr;
        }
    }
  }
}

// ---------------------------------------------------------------------------
// Transpose x [B][128][HW] -> x_t [B][16][HW][8]  (group-channel interleaved)
// and pre-fill d_out with bias (deform accumulates with atomicAdd).
// ---------------------------------------------------------------------------
__global__ __launch_bounds__(NTHR) void xpose_k(
    const float* __restrict__ x, const float* __restrict__ db,
    float* __restrict__ xt, float* __restrict__ out)
{
  constexpr int XT_N  = NB * DG * HW;        // 524,288 (b,g,pix) items
  constexpr int OUT_N = NB * DCN_COUT * HW;  // 2,097,152 bias fills
  const int total = XT_N + OUT_N;
  for (int gid = blockIdx.x * NTHR + threadIdx.x; gid < total;
       gid += gridDim.x * NTHR) {
    if (gid < XT_N) {
      const int b = gid / (DG * HW);
      const int r = gid - b * DG * HW;
      const int g = r / HW;
      const int p = r - g * HW;
      float4 v0, v1;
      const float* xs = x + ((size_t)(b * DCN_CIN) + g * CPG) * HW + p;
      v0.x = xs[0 * HW]; v0.y = xs[1 * HW]; v0.z = xs[2 * HW]; v0.w = xs[3 * HW];
      v1.x = xs[4 * HW]; v1.y = xs[5 * HW]; v1.z = xs[6 * HW]; v1.w = xs[7 * HW];
      float4* xd = (float4*)(xt + ((size_t)gid) * CPG);
      xd[0] = v0; xd[1] = v1;
    } else {
      const int k  = gid - XT_N;
      const int oc = (k / HW) & (DCN_COUT - 1);
      out[k] = db[oc];
    }
  }
}

// ---------------------------------------------------------------------------
// Modulated deformable conv, group-split. __launch_bounds__(256,4) caps
// occupancy at 4 waves/EU -> 128-VGPR budget so acc[64] stays in arch VGPRs
// (round-9 counters: VGPR_Count=60 => compiler put acc in AGPRs, every FMA
// paid accvgpr_read/write round-trip, ~3x VALU inflation).
// ---------------------------------------------------------------------------
template<int GPB>
__global__ __launch_bounds__(NTHR, 4) void deform_k(
    const float* __restrict__ xt,     // [B][16][HW][8]
    const float* __restrict__ o4,     // [B,432,H,W] activated offset+mask
    const float* __restrict__ dw,     // [64,128,3,3]
    float* __restrict__ out)          // [B,64,H,W] pre-filled with bias
{
  const int t    = threadIdx.x;
  const int tile = blockIdx.x;
  const int gc   = blockIdx.y;        // group chunk
  const int b    = blockIdx.z;
  const int lx   = t & 15, ly = t >> 4;
  const int hx   = (tile & 7) * 16 + lx;
  const int hy   = (tile >> 3) * 16 + ly;
  const int pix  = hy * W + hx;

  const float* ob = o4 + (size_t)(b * 432) * HW + pix;

  float acc[DCN_COUT];
  #pragma unroll
  for (int o = 0; o < DCN_COUT; ++o) acc[o] = 0.f;

  #pragma unroll 1
  for (int gi = 0; gi < GPB; ++gi) {
    const int g = gc * GPB + gi;
    const float* xg = xt + ((size_t)(b * DG + g)) * HW * CPG;

    #pragma unroll 1
    for (int k = 0; k < 9; ++k) {
      const int cb = g * 9 + k;
      const float oy = ob[(2 * cb + 0) * HW];
      const float ox = ob[(2 * cb + 1) * HW];
      const float mk = ob[(288 + cb) * HW];
      const float py  = (float)(hy + k / 3 - 1) + oy;
      const float pxx = (float)(hx + k % 3 - 1) + ox;
      const float y0f = floorf(py), x0f = floorf(pxx);
      const float wy = py - y0f, wx = pxx - x0f;
      const int y0 = (int)y0f, x0 = (int)x0f;
      const bool vy0 = (y0 >= 0) && (y0 < H);
      const bool vy1 = (y0 + 1 >= 0) && (y0 + 1 < H);
      const bool vx0 = (x0 >= 0) && (x0 < W);
      const bool vx1 = (x0 + 1 >= 0) && (x0 + 1 < W);
      const int cy0 = min(max(y0, 0), H - 1);
      const int cy1 = min(max(y0 + 1, 0), H - 1);
      const int cx0 = min(max(x0, 0), W - 1);
      const int cx1 = min(max(x0 + 1, 0), W - 1);
      const float w00 = (vy0 && vx0) ? (1.f - wy) * (1.f - wx) * mk : 0.f;
      const float w01 = (vy0 && vx1) ? (1.f - wy) * wx * mk : 0.f;
      const float w10 = (vy1 && vx0) ? wy * (1.f - wx) * mk : 0.f;
      const float w11 = (vy1 && vx1) ? wy * wx * mk : 0.f;

      const float4* p00 = (const float4*)(xg + (size_t)(cy0 * W + cx0) * CPG);
      const float4* p01 = (const float4*)(xg + (size_t)(cy0 * W + cx1) * CPG);
      const float4* p10 = (const float4*)(xg + (size_t)(cy1 * W + cx0) * CPG);
      const float4* p11 = (const float4*)(xg + (size_t)(cy1 * W + cx1) * CPG);
      const float4 a0 = p00[0], a1 = p00[1];
      const float4 b0 = p01[0], b1 = p01[1];
      const float4 c0 = p10[0], c1 = p10[1];
      const float4 d0 = p11[0], d1 = p11[1];

      float val[CPG];
      val[0] = fmaf(w00, a0.x, fmaf(w01, b0.x, fmaf(w10, c0.x, w11 * d0.x)));
      val[1] = fmaf(w00, a0.y, fmaf(w01, b0.y, fmaf(w10, c0.y, w11 * d0.y)));
      val[2] = fmaf(w00, a0.z, fmaf(w01, b0.z, fmaf(w10, c0.z, w11 * d0.z)));
      val[3] = fmaf(w00, a0.w, fmaf(w01, b0.w, fmaf(w10, c0.w, w11 * d0.w)));
      val[4] = fmaf(w00, a1.x, fmaf(w01, b1.x, fmaf(w10, c1.x, w11 * d1.x)));
      val[5] = fmaf(w00, a1.y, fmaf(w01, b1.y, fmaf(w10, c1.y, w11 * d1.y)));
      val[6] = fmaf(w00, a1.z, fmaf(w01, b1.z, fmaf(w10, c1.z, w11 * d1.z)));
      val[7] = fmaf(w00, a1.w, fmaf(w01, b1.w, fmaf(w10, c1.w, w11 * d1.w)));

      #pragma unroll
      for (int c = 0; c < CPG; ++c) {
        const float* wp = dw + (size_t)((g * CPG + c) * 9 + k);  // + o*1152
        #pragma unroll
        for (int o = 0; o < DCN_COUT; ++o)
          acc[o] = fmaf(val[c], wp[(size_t)o * (DCN_CIN * 9)], acc[o]);
      }
    }
  }

  float* ot = out + (size_t)(b * DCN_COUT) * HW + pix;
  #pragma unroll
  for (int o = 0; o < DCN_COUT; ++o)
    atomicAdd(ot + (size_t)o * HW, acc[o]);
}

// ---------------------------------------------------------------------------
extern "C" void kernel_launch(void* const* d_in, const int* in_sizes, int n_in,
                              void* d_out, int out_size, void* d_ws, size_t ws_size,
                              hipStream_t stream) {
  const float* x     = (const float*)d_in[0];
  const float* ef    = (const float*)d_in[1];
  const float* fl1   = (const float*)d_in[2];
  const float* fl2   = (const float*)d_in[3];
  const float* w1    = (const float*)d_in[4];
  const float* b1    = (const float*)d_in[5];
  const float* w2    = (const float*)d_in[6];
  const float* b2    = (const float*)d_in[7];
  const float* w3    = (const float*)d_in[8];
  const float* b3    = (const float*)d_in[9];
  const float* w4    = (const float*)d_in[10];
  const float* b4    = (const float*)d_in[11];
  const float* dcn_w = (const float*)d_in[12];
  const float* dcn_b = (const float*)d_in[13];

  float* ws  = (float*)d_ws;
  float* hA  = ws + OFF_HA;
  float* hB  = ws + OFF_HB;
  float* pin = ws + OFF_PIN;
  float* o4  = ws + OFF_O4;
  float* xt  = ws + OFF_XT;     // written after conv4 (hA/hB dead)

  const dim3 blk(NTHR);
  prep_k<<<2048, blk, 0, stream>>>(ef, fl1, fl2, pin, hA, hB);
  // conv1: 196 -> 64, leaky.  32x32 tiles, CC=4 -> 512 blocks
  conv3x3_k<196, 64, 4, 1><<<dim3(16, 16, NB), blk, 0, stream>>>(
      pin, w1, b1, nullptr, nullptr, hA);
  // conv2: 64 -> 64, leaky
  conv3x3_k<64, 64, 4, 1><<<dim3(16, 16, NB), blk, 0, stream>>>(
      hA, w2, b2, nullptr, nullptr, hB);
  // conv3: 64 -> 64, leaky
  conv3x3_k<64, 64, 4, 1><<<dim3(16, 16, NB), blk, 0, stream>>>(
      hB, w3, b3, nullptr, nullptr, hA);
  // conv4: 64 -> 432, fused offset/mask activation.  CC=16 -> 864 blocks
  conv3x3_k<64, 432, 16, 2><<<dim3(16, 27, NB), blk, 0, stream>>>(
      hA, w4, b4, fl1, fl2, o4);
  // transpose x for vectorized gathers + pre-fill out with bias
  xpose_k<<<2048, blk, 0, stream>>>(x, dcn_b, xt, (float*)d_out);
  // deformable conv: 8 group-chunks x 2 groups, atomic accumulate
  deform_k<2><<<dim3(64, 8, NB), blk, 0, stream>>>(xt, o4, dcn_w,
                                                   (float*)d_out);
}